// Round 9
// baseline (519.806 us; speedup 1.0000x reference)
//
#include <hip/hip_runtime.h>

#define NBATCH 32
#define NN     1024     // d_model = number of nodes
#define NF     128      // win_size = node feature dim
#define NDG    64       // graph embed dim
#define TOPK   15

// ---------------- workspace layout (bytes) ----------------
#define OFF_QH    ((size_t)0)            // bf16-hi q [32][1024][64]  4 MiB
#define OFF_QL    ((size_t)4194304)      // bf16-lo q                 4 MiB
#define OFF_KH    ((size_t)8388608)      // bf16-hi k                 4 MiB
#define OFF_KL    ((size_t)12582912)     // bf16-lo k                 4 MiB
#define OFF_H     ((size_t)16777216)     // f32 [32][1024][128]      16 MiB
#define OFF_DEG   ((size_t)33554432)     // i32 [32][1024]          128 KiB
#define OFF_BMP   ((size_t)33685504)     // u32 [32][1024][32]        4 MiB
#define OFF_WL    ((size_t)37879808)     // wl_cnt + wl[32767]      128 KiB
#define OFF_TOPK  ((size_t)38010880)     // i32 [32][1024][16]        2 MiB
#define OFF_W64   ((size_t)40108032)     // f64 Wq64[8192], Wk64[8192] 128 KiB
#define OFF_QT64  ((size_t)40239104)     // f64 [32][64][1024]       16 MiB
#define OFF_KT64  ((size_t)57016320)     // f64 [32][64][1024]       16 MiB
#define OFF_TMP   ((size_t)0)            // f32 [32][1024][128]      16 MiB (overlaps QH..KL, dead by then)

typedef short s8v  __attribute__((ext_vector_type(8)));   // 8 bf16 (4 VGPRs) MFMA operand
typedef float f4v  __attribute__((ext_vector_type(4)));   // MFMA accumulator
typedef unsigned short us8v __attribute__((ext_vector_type(8)));

__device__ inline unsigned short bf16_rne(float f) {
    unsigned u = __float_as_uint(f);
    return (unsigned short)((u + 0x7FFFu + ((u >> 16) & 1u)) >> 16);
}
__device__ inline float bf16_tof(unsigned short h) { return __uint_as_float(((unsigned)h) << 16); }

// monotone 16-bit code for f32 score in window [-4, 4): sign + 5-bit biased exp + 10-bit mantissa.
// quantum = 2^12 f32-ULP (≈ 2^-11 at |s| in [1,2)); ties/truncation handled by repair margin.
__device__ inline unsigned short pack16(float s) {
    unsigned u   = __float_as_uint(s);
    int      mag = (int)(u & 0x7FFFFFFFu);
    int      t   = mag - 0x38800000;                 // bias at 2^-14
    t = t < 0 ? 0 : (t > 0x07FFFFFF ? 0x07FFFFFF : t);
    unsigned ts = (unsigned)t >> 12;                 // 15 bits
    return (unsigned short)(((int)u < 0) ? (0x7FFFu - ts) : (0x8000u | ts));
}
__device__ inline float dec16(unsigned c) {
    bool pos = (c & 0x8000u) != 0;
    unsigned ts = pos ? (c & 0x7FFFu) : (0x7FFFu - c);
    float f = __uint_as_float((ts << 12) + 0x38800000u);
    return pos ? f : -f;
}

__global__ __launch_bounds__(256) void k_upcast(const float* __restrict__ Wq,
                                                const float* __restrict__ Wk,
                                                double* __restrict__ Wq64,
                                                double* __restrict__ Wk64) {
    int i = blockIdx.x * 256 + threadIdx.x;  // 0..8191
    Wq64[i] = (double)Wq[i];
    Wk64[i] = (double)Wk[i];
}

// Fused: zero deg/bmp/wl_cnt + q,k f64 (repair path) + bf16 hi/lo splits + h = nf@Wg.T.
// grid (16 node-tiles, 2 halves, 32 batch), block 256. lane = node within 64-node tile.
__global__ __launch_bounds__(256) void k_prep(
    const float* __restrict__ x, const float* __restrict__ bq, const float* __restrict__ bk,
    const double* __restrict__ Wq64, const double* __restrict__ Wk64,
    const float* __restrict__ Wg,
    unsigned short* __restrict__ qh, unsigned short* __restrict__ ql,
    unsigned short* __restrict__ kh, unsigned short* __restrict__ kl,
    double* __restrict__ qT64, double* __restrict__ kT64,
    float* __restrict__ h,
    uint4* __restrict__ zbase, int zn)
{
    __shared__ float xs[64 * 129];   // xs[node][f], pad 129 -> conflict-free
    const int t = threadIdx.x;
    const int l = t & 63;
    const int w = t >> 6;
    const int uw = __builtin_amdgcn_readfirstlane(w);
    const int n0 = blockIdx.x * 64;
    const int half = blockIdx.y;
    const int b  = blockIdx.z;

    // --- zero phase (deg + bmp + wl_cnt), grid-stride over 1024 blocks ---
    {
        int lid = ((b * 2 + half) * 16 + blockIdx.x) * 256 + t;   // 0..262143
        for (int i = lid; i < zn; i += 262144)
            zbase[i] = make_uint4(0u, 0u, 0u, 0u);
    }

    {   // xs[node][f] = x[b][f][n0+node]  (coalesced over node)
        const int j = t & 63, fg = t >> 6;
        for (int ff = 0; ff < 32; ++ff) {
            int f = fg + ff * 4;
            xs[j * 129 + f] = x[((size_t)b * NF + f) * NN + n0 + j];
        }
    }
    __syncthreads();

    // --- q/k phase (f64, 8 d-dims per wave) ---
    {
        const int d0 = half * 32 + uw * 8;
        double accq[8], acck[8];
        #pragma unroll
        for (int dd = 0; dd < 8; ++dd) {
            accq[dd] = (double)bq[d0 + dd];
            acck[dd] = (double)bk[d0 + dd];
        }
        for (int fc = 0; fc < 32; ++fc) {
            double dx0 = (double)xs[l * 129 + fc * 4 + 0];
            double dx1 = (double)xs[l * 129 + fc * 4 + 1];
            double dx2 = (double)xs[l * 129 + fc * 4 + 2];
            double dx3 = (double)xs[l * 129 + fc * 4 + 3];
            #pragma unroll
            for (int dd = 0; dd < 8; ++dd) {
                int d = d0 + dd;   // uniform -> scalar loads of weights
                const double* wq = &Wq64[d * NF + fc * 4];
                const double* wk = &Wk64[d * NF + fc * 4];
                accq[dd] += dx0 * wq[0] + dx1 * wq[1] + dx2 * wq[2] + dx3 * wq[3];
                acck[dd] += dx0 * wk[0] + dx1 * wk[1] + dx2 * wk[2] + dx3 * wk[3];
            }
        }
        // f64 [d][n] for repair (coalesced over lane)
        #pragma unroll
        for (int dd = 0; dd < 8; ++dd) {
            size_t idx = ((size_t)b * NDG + d0 + dd) * NN + n0 + l;
            qT64[idx] = accq[dd];
            kT64[idx] = acck[dd];
        }
        // bf16 hi/lo splits, [n][d] layout
        us8v qh0, ql0, kh0, kl0;
        #pragma unroll
        for (int dd = 0; dd < 8; ++dd) {
            float fq = (float)accq[dd];
            unsigned short h1 = bf16_rne(fq);
            unsigned short l1 = bf16_rne(fq - bf16_tof(h1));
            float fk = (float)acck[dd];
            unsigned short h2 = bf16_rne(fk);
            unsigned short l2 = bf16_rne(fk - bf16_tof(h2));
            qh0[dd] = h1; ql0[dd] = l1; kh0[dd] = h2; kl0[dd] = l2;
        }
        size_t nb = ((size_t)b * NN + n0 + l) * NDG + d0;
        *(us8v*)&qh[nb] = qh0;
        *(us8v*)&ql[nb] = ql0;
        *(us8v*)&kh[nb] = kh0;
        *(us8v*)&kl[nb] = kl0;
    }

    // --- h phase (f32, 16 out-features per wave; this block covers f' in [half*64, half*64+64)) ---
    {
        const int fp0 = half * 64 + uw * 16;
        float acc[16];
        #pragma unroll
        for (int i = 0; i < 16; ++i) acc[i] = 0.f;
        for (int fc = 0; fc < 32; ++fc) {
            float x0 = xs[l * 129 + fc * 4 + 0];
            float x1 = xs[l * 129 + fc * 4 + 1];
            float x2 = xs[l * 129 + fc * 4 + 2];
            float x3 = xs[l * 129 + fc * 4 + 3];
            #pragma unroll
            for (int ff = 0; ff < 16; ++ff) {
                const float* wg = &Wg[(fp0 + ff) * NF + fc * 4];
                acc[ff] += x0 * wg[0] + x1 * wg[1] + x2 * wg[2] + x3 * wg[3];
            }
        }
        __syncthreads();   // everyone done reading xs
        #pragma unroll
        for (int ff = 0; ff < 16; ++ff) xs[l * 129 + fp0 + ff] = acc[ff];
        __syncthreads();
        // write h[n][half*64 .. half*64+64) for the 64 nodes
        for (int r = 0; r < 16; ++r) {
            int idx = t + 256 * r;            // 0..4095
            int n = idx >> 6, f = idx & 63;
            h[((size_t)b * NN + n0 + n) * NF + half * 64 + f] = xs[n * 129 + half * 64 + f];
        }
    }
}

#define CE(x,y) { unsigned a_ = v[x], b_ = v[y]; v[x] = a_ > b_ ? a_ : b_; v[y] = a_ > b_ ? b_ : a_; }
__device__ inline void sort16(unsigned v[16]) {
    // Batcher odd-even mergesort 16, descending (63 CE)
    CE(0,1) CE(2,3) CE(4,5) CE(6,7) CE(8,9) CE(10,11) CE(12,13) CE(14,15)
    CE(0,2) CE(1,3) CE(4,6) CE(5,7) CE(8,10) CE(9,11) CE(12,14) CE(13,15)
    CE(1,2) CE(5,6) CE(9,10) CE(13,14)
    CE(0,4) CE(1,5) CE(2,6) CE(3,7) CE(8,12) CE(9,13) CE(10,14) CE(11,15)
    CE(2,4) CE(3,5) CE(10,12) CE(11,13)
    CE(1,2) CE(3,4) CE(5,6) CE(9,10) CE(11,12) CE(13,14)
    CE(0,8) CE(1,9) CE(2,10) CE(3,11) CE(4,12) CE(5,13) CE(6,14) CE(7,15)
    CE(4,8) CE(5,9) CE(6,10) CE(7,11)
    CE(2,4) CE(3,5) CE(6,8) CE(7,9) CE(10,12) CE(11,13)
    CE(1,2) CE(3,4) CE(5,6) CE(7,8) CE(9,10) CE(11,12) CE(13,14)
}
// bitonic clean, 16 elements, descending (32 CE): input bitonic
__device__ inline void clean16(unsigned v[16]) {
    CE(0,8) CE(1,9) CE(2,10) CE(3,11) CE(4,12) CE(5,13) CE(6,14) CE(7,15)
    CE(0,4) CE(1,5) CE(2,6) CE(3,7) CE(8,12) CE(9,13) CE(10,14) CE(11,15)
    CE(0,2) CE(1,3) CE(4,6) CE(5,7) CE(8,10) CE(9,11) CE(12,14) CE(13,15)
    CE(0,1) CE(2,3) CE(4,5) CE(6,7) CE(8,9) CE(10,11) CE(12,13) CE(14,15)
}

// MFMA bf16-split scores + packed top-15 via butterfly merge-tree + deg/bitmap atomics + worklist.
// grid (64, 32), block 512 (8 waves): wave w computes cols [128w,128w+128); selects rows {2w,2w+1}.
// LDS stores 16-bit value codes only (col recovered from index): 32 KiB -> 4 blocks/CU.
__global__ __launch_bounds__(512, 4) void k_score(
    const unsigned short* __restrict__ qh, const unsigned short* __restrict__ ql,
    const unsigned short* __restrict__ kh, const unsigned short* __restrict__ kl,
    int* __restrict__ deg, unsigned int* __restrict__ bmp,
    int* __restrict__ topk, int* __restrict__ wl_cnt, int* __restrict__ wl)
{
    __shared__ unsigned short pk[16 * 1024];    // packed value codes, 32 KiB
    const int t = threadIdx.x, l = t & 63, w = t >> 6;   // w in [0,8)
    const int b = blockIdx.y, row0 = blockIdx.x * 16;
    const int m = l & 15, q4 = l >> 4;

    // A fragments: 16 q rows (hi/lo, two K-halves). A[m][k]: m=lane&15, k=(lane>>4)*8+j
    size_t abase = ((size_t)b * NN + row0 + m) * NDG + q4 * 8;
    s8v ah0 = *(const s8v*)&qh[abase];
    s8v ah1 = *(const s8v*)&qh[abase + 32];
    s8v al0 = *(const s8v*)&ql[abase];
    s8v al1 = *(const s8v*)&ql[abase + 32];

    const int colbase = w * 128;
    #pragma unroll
    for (int tt = 0; tt < 8; ++tt) {
        int col = colbase + tt * 16 + m;
        size_t bbase = ((size_t)b * NN + col) * NDG + q4 * 8;
        s8v bh0 = *(const s8v*)&kh[bbase];
        s8v bh1 = *(const s8v*)&kh[bbase + 32];
        s8v bl0 = *(const s8v*)&kl[bbase];
        s8v bl1 = *(const s8v*)&kl[bbase + 32];
        f4v acc = {0.f, 0.f, 0.f, 0.f};
        acc = __builtin_amdgcn_mfma_f32_16x16x32_bf16(al0, bl0, acc, 0, 0, 0);
        acc = __builtin_amdgcn_mfma_f32_16x16x32_bf16(al1, bl1, acc, 0, 0, 0);
        acc = __builtin_amdgcn_mfma_f32_16x16x32_bf16(ah0, bl0, acc, 0, 0, 0);
        acc = __builtin_amdgcn_mfma_f32_16x16x32_bf16(ah1, bl1, acc, 0, 0, 0);
        acc = __builtin_amdgcn_mfma_f32_16x16x32_bf16(al0, bh0, acc, 0, 0, 0);
        acc = __builtin_amdgcn_mfma_f32_16x16x32_bf16(al1, bh1, acc, 0, 0, 0);
        acc = __builtin_amdgcn_mfma_f32_16x16x32_bf16(ah0, bh0, acc, 0, 0, 0);
        acc = __builtin_amdgcn_mfma_f32_16x16x32_bf16(ah1, bh1, acc, 0, 0, 0);
        // C/D: col=lane&15, row=(lane>>4)*4+reg. Write XOR-swizzled (q4<<4) = ((row>>2)<<4):
        // reader uses the same swizzle, so col = index ^ swz. ushort: 2 lanes/bank = free.
        #pragma unroll
        for (int r = 0; r < 4; ++r) {
            int row  = q4 * 4 + r;           // local 0..15
            int grow = row0 + row;
            float s = acc[r] * 0.125f;
            unsigned short p = (col == grow) ? (unsigned short)0 : pack16(s);
            pk[row * 1024 + (col ^ (q4 << 4))] = p;
        }
    }
    __syncthreads();

    // wave w selects rows 2w, 2w+1 via butterfly merge-tree; all lanes end with global top-16
    for (int rr = 0; rr < 2; ++rr) {
        const int row = 2 * w + rr, grow = row0 + row;
        const int swz = (row >> 2) << 4;
        unsigned v[16];
        #pragma unroll
        for (int j = 0; j < 16; ++j) {
            unsigned code = pk[row * 1024 + ((l + 64 * j) ^ swz)];   // this index holds col = l+64j
            v[j] = (code << 10) | (unsigned)(1023 - (l + 64 * j));
        }
        sort16(v);
        #pragma unroll
        for (int off = 1; off < 64; off <<= 1) {
            unsigned pv[16];
            #pragma unroll
            for (int i = 0; i < 16; ++i) pv[i] = (unsigned)__shfl_xor((int)v[i], off, 64);
            #pragma unroll
            for (int i = 0; i < 8; ++i) {   // c[i]=max(v[i],pv[15-i]) in place (i and 15-i swap-safe)
                unsigned a0 = v[i], b0 = pv[15 - i];
                unsigned a1 = v[15 - i], b1 = pv[i];
                v[i]      = a0 > b0 ? a0 : b0;
                v[15 - i] = a1 > b1 ? a1 : b1;
            }
            clean16(v);
        }
        // v[0..14] = top-15 desc; v[14]=15th, v[15]=16th
        float s15 = dec16(v[14] >> 10), s16 = dec16(v[15] >> 10);
        unsigned e15 = (__float_as_uint(fabsf(s15)) >> 23) & 255u;
        unsigned e16 = (__float_as_uint(fabsf(s16)) >> 23) & 255u;
        unsigned e = e15 > e16 ? e15 : e16;
        float qq = __uint_as_float((e - 11) << 23);    // 16-bit code quantum at this magnitude
        bool flagged = (s15 - s16) < (4.f * qq + 1e-4f);
        if (l < 15) {
            int col = 1023 - (int)(v[l] & 1023u);
            atomicAdd(&deg[b * NN + col], 1);
            atomicOr(&bmp[((size_t)b * NN + col) * 32 + (grow >> 5)], 1u << (grow & 31));
            if (flagged) topk[(b * NN + grow) * 16 + l] = col;
        }
        if (l == 0 && flagged) {
            int idx = atomicAdd(wl_cnt, 1);
            if (idx < 32767) wl[idx] = b * NN + grow;
        }
    }
}

// exact f64 re-selection for worklist rows; patches deg/bitmap by set-diff.
// grid 1024, block 64: ~one block per flagged row, fully concurrent; d-loop double-buffered.
__global__ __launch_bounds__(64) void k_repair(
    const double* __restrict__ qT64, const double* __restrict__ kT64,
    const int* __restrict__ topk, const int* __restrict__ wl_cnt, const int* __restrict__ wl,
    int* __restrict__ deg, unsigned int* __restrict__ bmp)
{
    const int l = threadIdx.x;
    __shared__ double qld[64];
    __shared__ int oldset[15], newset[15];
    const double NEGINF = -__builtin_inf();
    int n = wl_cnt[0]; if (n > 32767) n = 32767;

    for (int i = blockIdx.x; i < n; i += 1024) {
        int rg = wl[i];
        int b = rg >> 10, row = rg & 1023;

        __syncthreads();
        qld[l] = qT64[((size_t)b * NDG + l) * NN + row];
        if (l < 15) oldset[l] = topk[(b * NN + row) * 16 + l];
        __syncthreads();

        double sc[16];
        #pragma unroll
        for (int tt = 0; tt < 16; ++tt) sc[tt] = 0.0;
        const double* kb = &kT64[(size_t)b * NDG * NN];
        double buf[16];
        #pragma unroll
        for (int tt = 0; tt < 16; ++tt) buf[tt] = kb[l + 64 * tt];
        for (int d = 0; d < 64; ++d) {
            double nb[16];
            if (d < 63) {
                const double* kr = kb + (size_t)(d + 1) * NN;
                #pragma unroll
                for (int tt = 0; tt < 16; ++tt) nb[tt] = kr[l + 64 * tt];
            }
            double qd = qld[d];
            #pragma unroll
            for (int tt = 0; tt < 16; ++tt) sc[tt] += qd * buf[tt];
            if (d < 63) {
                #pragma unroll
                for (int tt = 0; tt < 16; ++tt) buf[tt] = nb[tt];
            }
        }
        #pragma unroll
        for (int tt = 0; tt < 16; ++tt) if (l + 64 * tt == row) sc[tt] = NEGINF;

        for (int it = 0; it < 15; ++it) {
            double lv = NEGINF; int lc = 0x7fffffff;
            #pragma unroll
            for (int tt = 0; tt < 16; ++tt)
                if (sc[tt] > lv) { lv = sc[tt]; lc = l + 64 * tt; }
            #pragma unroll
            for (int off = 1; off < 64; off <<= 1) {
                double ov = __shfl_xor(lv, off, 64);
                int    oc = __shfl_xor(lc, off, 64);
                if (ov > lv || (ov == lv && oc < lc)) { lv = ov; lc = oc; }
            }
            #pragma unroll
            for (int tt = 0; tt < 16; ++tt) if (l + 64 * tt == lc) sc[tt] = NEGINF;
            if (l == 0) newset[it] = lc;
        }
        __syncthreads();
        if (l < 15) {
            int cn = newset[l];
            bool found = false;
            #pragma unroll
            for (int j = 0; j < 15; ++j) found = found || (oldset[j] == cn);
            if (!found) {
                atomicAdd(&deg[b * NN + cn], 1);
                atomicOr(&bmp[((size_t)b * NN + cn) * 32 + (row >> 5)], 1u << (row & 31));
            }
            int co = oldset[l];
            found = false;
            #pragma unroll
            for (int j = 0; j < 15; ++j) found = found || (newset[j] == co);
            if (!found) {
                atomicSub(&deg[b * NN + co], 1);
                atomicAnd(&bmp[((size_t)b * NN + co) * 32 + (row >> 5)], ~(1u << (row & 31)));
            }
        }
    }
}

// gather per target via compacted LDS edge list + LDS norm table (dinv folded here).
// grid (1024,32), block 128 (f = thread).
__global__ __launch_bounds__(128) void k_gather(
    const float* __restrict__ h, const float* __restrict__ bg,
    const int* __restrict__ deg, const unsigned int* __restrict__ bmp,
    float* __restrict__ tmp)
{
    __shared__ int list[1024];
    __shared__ float nrm[1024];
    __shared__ int scnt;
    const int tgt = blockIdx.x, b = blockIdx.y, t = threadIdx.x;
    if (t < 32) {
        unsigned word = bmp[((size_t)b * NN + tgt) * 32 + t];
        int pc = __popc(word);
        int pre = pc;
        #pragma unroll
        for (int d = 1; d < 32; d <<= 1) {
            int o = __shfl_up(pre, d, 32);
            if (t >= d) pre += o;
        }
        if (t == 31) scnt = pre;
        int idx = pre - pc;
        while (word) {
            int s = __ffs(word) - 1;
            word &= word - 1;
            list[idx++] = t * 32 + s;
        }
    }
    __syncthreads();
    const int cnt = scnt;
    for (int e = t; e < cnt; e += 128)
        nrm[e] = rsqrtf((float)(deg[b * NN + list[e]] + 2));
    __syncthreads();
    const int f = t;
    float dt = rsqrtf((float)(deg[b * NN + tgt] + 2));
    float acc = 2.0f * dt * h[((size_t)b * NN + tgt) * NF + f];
    for (int e = 0; e < cnt; ++e) {
        int src = list[e];
        acc += h[((size_t)b * NN + src) * NF + f] * nrm[e];
    }
    tmp[((size_t)b * NN + tgt) * NF + f] = bg[f] + dt * acc;
}

// [b][n][f] -> [b][f][n]. grid (32, 4, 32), block 256.
__global__ __launch_bounds__(256) void k_transpose(const float* __restrict__ tmp,
                                                   float* __restrict__ out)
{
    __shared__ float tile[32][33];
    const int t = threadIdx.x;
    const int n0 = blockIdx.x * 32, f0 = blockIdx.y * 32, b = blockIdx.z;
    const int c = t & 31, rb = t >> 5;
    #pragma unroll
    for (int i = 0; i < 4; ++i) {
        int r = rb + i * 8;
        tile[r][c] = tmp[((size_t)b * NN + n0 + r) * NF + f0 + c];
    }
    __syncthreads();
    #pragma unroll
    for (int i = 0; i < 4; ++i) {
        int r = rb + i * 8;
        out[((size_t)b * NF + f0 + r) * NN + n0 + c] = tile[c][r];
    }
}

extern "C" void kernel_launch(void* const* d_in, const int* in_sizes, int n_in,
                              void* d_out, int out_size, void* d_ws, size_t ws_size,
                              hipStream_t stream)
{
    const float* x  = (const float*)d_in[0];
    const float* Wq = (const float*)d_in[1];
    const float* bq = (const float*)d_in[2];
    const float* Wk = (const float*)d_in[3];
    const float* bk = (const float*)d_in[4];
    const float* Wg = (const float*)d_in[5];
    const float* bg = (const float*)d_in[6];
    float* out = (float*)d_out;
    char* ws = (char*)d_ws;

    unsigned short* qh = (unsigned short*)(ws + OFF_QH);
    unsigned short* ql = (unsigned short*)(ws + OFF_QL);
    unsigned short* kh = (unsigned short*)(ws + OFF_KH);
    unsigned short* kl = (unsigned short*)(ws + OFF_KL);
    float*          h   = (float*)(ws + OFF_H);
    int*            deg = (int*)(ws + OFF_DEG);
    unsigned int*   bmp = (unsigned int*)(ws + OFF_BMP);
    int*            wlc = (int*)(ws + OFF_WL);
    int*            wl  = wlc + 1;
    int*            tpk = (int*)(ws + OFF_TOPK);
    double*         Wq64 = (double*)(ws + OFF_W64);
    double*         Wk64 = Wq64 + 8192;
    double*         qT64 = (double*)(ws + OFF_QT64);
    double*         kT64 = (double*)(ws + OFF_KT64);
    float*          tmp  = (float*)(ws + OFF_TMP);

    k_upcast<<<32, 256, 0, stream>>>(Wq, Wk, Wq64, Wk64);
    // zero range: deg + bmp + wl_cnt = 4,325,392 B = 270337 uint4 (done inside k_prep)
    k_prep<<<dim3(16, 2, 32), 256, 0, stream>>>(x, bq, bk, Wq64, Wk64, Wg,
                                                qh, ql, kh, kl, qT64, kT64, h,
                                                (uint4*)(ws + OFF_DEG), 270337);
    k_score<<<dim3(64, 32), 512, 0, stream>>>(qh, ql, kh, kl, deg, bmp, tpk, wlc, wl);
    k_repair<<<1024, 64, 0, stream>>>(qT64, kT64, tpk, wlc, wl, deg, bmp);
    k_gather<<<dim3(1024, 32), 128, 0, stream>>>(h, bg, deg, bmp, tmp);
    k_transpose<<<dim3(32, 4, 32), 256, 0, stream>>>(tmp, out);
}

// Round 10
// 313.361 us; speedup vs baseline: 1.6588x; 1.6588x over previous
//
#include <hip/hip_runtime.h>

#define NBATCH 32
#define NN     1024     // d_model = number of nodes
#define NF     128      // win_size = node feature dim
#define NDG    64       // graph embed dim
#define TOPK   15

// ---------------- workspace layout (bytes) ----------------
#define OFF_QH    ((size_t)0)            // bf16-hi q [32][1024][64]  4 MiB
#define OFF_QL    ((size_t)4194304)      // bf16-lo q                 4 MiB
#define OFF_KH    ((size_t)8388608)      // bf16-hi k                 4 MiB
#define OFF_KL    ((size_t)12582912)     // bf16-lo k                 4 MiB
#define OFF_H     ((size_t)16777216)     // f32 [32][1024][128]      16 MiB
#define OFF_DEG   ((size_t)33554432)     // i32 [32][1024]          128 KiB
#define OFF_BMP   ((size_t)33685504)     // u32 [32][1024][32]        4 MiB
#define OFF_WL    ((size_t)37879808)     // wl_cnt + wl[32767]      128 KiB
#define OFF_TOPK  ((size_t)38010880)     // i32 [32][1024][16]        2 MiB
#define OFF_W64   ((size_t)40108032)     // f64 Wq64[8192], Wk64[8192] 128 KiB
#define OFF_QT64  ((size_t)40239104)     // f64 [32][64][1024]       16 MiB
#define OFF_KT64  ((size_t)57016320)     // f64 [32][64][1024]       16 MiB
#define OFF_TMP   ((size_t)0)            // f32 [32][1024][128]      16 MiB (overlaps QH..KL, dead by then)

typedef short s8v  __attribute__((ext_vector_type(8)));   // 8 bf16 (4 VGPRs) MFMA operand
typedef float f4v  __attribute__((ext_vector_type(4)));   // MFMA accumulator
typedef unsigned short us8v __attribute__((ext_vector_type(8)));

__device__ inline unsigned short bf16_rne(float f) {
    unsigned u = __float_as_uint(f);
    return (unsigned short)((u + 0x7FFFu + ((u >> 16) & 1u)) >> 16);
}
__device__ inline float bf16_tof(unsigned short h) { return __uint_as_float(((unsigned)h) << 16); }

// monotone 22-bit code for f32 score in window [-4, 4): sign + 5-bit biased exp + 16-bit mantissa
__device__ inline unsigned pack22(float s) {
    unsigned u   = __float_as_uint(s);
    int      mag = (int)(u & 0x7FFFFFFFu);
    int      t   = mag - 0x38800000;                 // bias at 2^-14
    t = t < 0 ? 0 : (t > 0x07FFFFFF ? 0x07FFFFFF : t);
    unsigned ts = (unsigned)t >> 6;                  // 21 bits
    return ((int)u < 0) ? (0x1FFFFFu - ts) : (0x200000u | ts);
}
__device__ inline float dec22(unsigned val22) {
    bool pos = (val22 & 0x200000u) != 0;
    unsigned ts = pos ? (val22 & 0x1FFFFFu) : (0x1FFFFFu - (val22 & 0x1FFFFFu));
    float f = __uint_as_float((ts << 6) + 0x38800000u);
    return pos ? f : -f;
}

__global__ __launch_bounds__(256) void k_upcast(const float* __restrict__ Wq,
                                                const float* __restrict__ Wk,
                                                double* __restrict__ Wq64,
                                                double* __restrict__ Wk64) {
    int i = blockIdx.x * 256 + threadIdx.x;  // 0..8191
    Wq64[i] = (double)Wq[i];
    Wk64[i] = (double)Wk[i];
}

// Fused: zero deg/bmp/wl_cnt + q,k f64 (repair path) + bf16 hi/lo splits + h = nf@Wg.T.
// grid (16 node-tiles, 2 halves, 32 batch), block 256. lane = node within 64-node tile.
__global__ __launch_bounds__(256) void k_prep(
    const float* __restrict__ x, const float* __restrict__ bq, const float* __restrict__ bk,
    const double* __restrict__ Wq64, const double* __restrict__ Wk64,
    const float* __restrict__ Wg,
    unsigned short* __restrict__ qh, unsigned short* __restrict__ ql,
    unsigned short* __restrict__ kh, unsigned short* __restrict__ kl,
    double* __restrict__ qT64, double* __restrict__ kT64,
    float* __restrict__ h,
    uint4* __restrict__ zbase, int zn)
{
    __shared__ float xs[64 * 129];   // xs[node][f], pad 129 -> conflict-free
    const int t = threadIdx.x;
    const int l = t & 63;
    const int w = t >> 6;
    const int uw = __builtin_amdgcn_readfirstlane(w);
    const int n0 = blockIdx.x * 64;
    const int half = blockIdx.y;
    const int b  = blockIdx.z;

    // --- zero phase (deg + bmp + wl_cnt), grid-stride over 1024 blocks ---
    {
        int lid = ((b * 2 + half) * 16 + blockIdx.x) * 256 + t;   // 0..262143
        for (int i = lid; i < zn; i += 262144)
            zbase[i] = make_uint4(0u, 0u, 0u, 0u);
    }

    {   // xs[node][f] = x[b][f][n0+node]  (coalesced over node)
        const int j = t & 63, fg = t >> 6;
        for (int ff = 0; ff < 32; ++ff) {
            int f = fg + ff * 4;
            xs[j * 129 + f] = x[((size_t)b * NF + f) * NN + n0 + j];
        }
    }
    __syncthreads();

    // --- q/k phase (f64, 8 d-dims per wave) ---
    {
        const int d0 = half * 32 + uw * 8;
        double accq[8], acck[8];
        #pragma unroll
        for (int dd = 0; dd < 8; ++dd) {
            accq[dd] = (double)bq[d0 + dd];
            acck[dd] = (double)bk[d0 + dd];
        }
        for (int fc = 0; fc < 32; ++fc) {
            double dx0 = (double)xs[l * 129 + fc * 4 + 0];
            double dx1 = (double)xs[l * 129 + fc * 4 + 1];
            double dx2 = (double)xs[l * 129 + fc * 4 + 2];
            double dx3 = (double)xs[l * 129 + fc * 4 + 3];
            #pragma unroll
            for (int dd = 0; dd < 8; ++dd) {
                int d = d0 + dd;   // uniform -> scalar loads of weights
                const double* wq = &Wq64[d * NF + fc * 4];
                const double* wk = &Wk64[d * NF + fc * 4];
                accq[dd] += dx0 * wq[0] + dx1 * wq[1] + dx2 * wq[2] + dx3 * wq[3];
                acck[dd] += dx0 * wk[0] + dx1 * wk[1] + dx2 * wk[2] + dx3 * wk[3];
            }
        }
        // f64 [d][n] for repair (coalesced over lane)
        #pragma unroll
        for (int dd = 0; dd < 8; ++dd) {
            size_t idx = ((size_t)b * NDG + d0 + dd) * NN + n0 + l;
            qT64[idx] = accq[dd];
            kT64[idx] = acck[dd];
        }
        // bf16 hi/lo splits, [n][d] layout
        us8v qh0, ql0, kh0, kl0;
        #pragma unroll
        for (int dd = 0; dd < 8; ++dd) {
            float fq = (float)accq[dd];
            unsigned short h1 = bf16_rne(fq);
            unsigned short l1 = bf16_rne(fq - bf16_tof(h1));
            float fk = (float)acck[dd];
            unsigned short h2 = bf16_rne(fk);
            unsigned short l2 = bf16_rne(fk - bf16_tof(h2));
            qh0[dd] = h1; ql0[dd] = l1; kh0[dd] = h2; kl0[dd] = l2;
        }
        size_t nb = ((size_t)b * NN + n0 + l) * NDG + d0;
        *(us8v*)&qh[nb] = qh0;
        *(us8v*)&ql[nb] = ql0;
        *(us8v*)&kh[nb] = kh0;
        *(us8v*)&kl[nb] = kl0;
    }

    // --- h phase (f32, 16 out-features per wave; this block covers f' in [half*64, half*64+64)) ---
    {
        const int fp0 = half * 64 + uw * 16;
        float acc[16];
        #pragma unroll
        for (int i = 0; i < 16; ++i) acc[i] = 0.f;
        for (int fc = 0; fc < 32; ++fc) {
            float x0 = xs[l * 129 + fc * 4 + 0];
            float x1 = xs[l * 129 + fc * 4 + 1];
            float x2 = xs[l * 129 + fc * 4 + 2];
            float x3 = xs[l * 129 + fc * 4 + 3];
            #pragma unroll
            for (int ff = 0; ff < 16; ++ff) {
                const float* wg = &Wg[(fp0 + ff) * NF + fc * 4];
                acc[ff] += x0 * wg[0] + x1 * wg[1] + x2 * wg[2] + x3 * wg[3];
            }
        }
        __syncthreads();   // everyone done reading xs
        #pragma unroll
        for (int ff = 0; ff < 16; ++ff) xs[l * 129 + fp0 + ff] = acc[ff];
        __syncthreads();
        // write h[n][half*64 .. half*64+64) for the 64 nodes
        for (int r = 0; r < 16; ++r) {
            int idx = t + 256 * r;            // 0..4095
            int n = idx >> 6, f = idx & 63;
            h[((size_t)b * NN + n0 + n) * NF + half * 64 + f] = xs[n * 129 + half * 64 + f];
        }
    }
}

#define CE(x,y) { unsigned a_ = v[x], b_ = v[y]; v[x] = a_ > b_ ? a_ : b_; v[y] = a_ > b_ ? b_ : a_; }
__device__ inline void sort16(unsigned v[16]) {
    // Batcher odd-even mergesort 16, descending (63 CE)
    CE(0,1) CE(2,3) CE(4,5) CE(6,7) CE(8,9) CE(10,11) CE(12,13) CE(14,15)
    CE(0,2) CE(1,3) CE(4,6) CE(5,7) CE(8,10) CE(9,11) CE(12,14) CE(13,15)
    CE(1,2) CE(5,6) CE(9,10) CE(13,14)
    CE(0,4) CE(1,5) CE(2,6) CE(3,7) CE(8,12) CE(9,13) CE(10,14) CE(11,15)
    CE(2,4) CE(3,5) CE(10,12) CE(11,13)
    CE(1,2) CE(3,4) CE(5,6) CE(9,10) CE(11,12) CE(13,14)
    CE(0,8) CE(1,9) CE(2,10) CE(3,11) CE(4,12) CE(5,13) CE(6,14) CE(7,15)
    CE(4,8) CE(5,9) CE(6,10) CE(7,11)
    CE(2,4) CE(3,5) CE(6,8) CE(7,9) CE(10,12) CE(11,13)
    CE(1,2) CE(3,4) CE(5,6) CE(7,8) CE(9,10) CE(11,12) CE(13,14)
}
// bitonic clean, 16 elements, descending (32 CE): input bitonic
__device__ inline void clean16(unsigned v[16]) {
    CE(0,8) CE(1,9) CE(2,10) CE(3,11) CE(4,12) CE(5,13) CE(6,14) CE(7,15)
    CE(0,4) CE(1,5) CE(2,6) CE(3,7) CE(8,12) CE(9,13) CE(10,14) CE(11,15)
    CE(0,2) CE(1,3) CE(4,6) CE(5,7) CE(8,10) CE(9,11) CE(12,14) CE(13,15)
    CE(0,1) CE(2,3) CE(4,5) CE(6,7) CE(8,9) CE(10,11) CE(12,13) CE(14,15)
}

// MFMA bf16-split scores + packed top-15 via butterfly merge-tree + deg/bitmap atomics + worklist.
// grid (64, 32), block 512 (8 waves): wave w computes cols [128w,128w+128); selects rows {2w,2w+1}.
// LDS: full 22-bit value code split hi16 (ushort, 32 KiB) + lo6 (byte, 16 KiB) = 48 KiB -> 3 blocks/CU.
// col recovered from the self-inverse XOR-swizzled index.
__global__ __launch_bounds__(512, 4) void k_score(
    const unsigned short* __restrict__ qh, const unsigned short* __restrict__ ql,
    const unsigned short* __restrict__ kh, const unsigned short* __restrict__ kl,
    int* __restrict__ deg, unsigned int* __restrict__ bmp,
    int* __restrict__ topk, int* __restrict__ wl_cnt, int* __restrict__ wl)
{
    __shared__ unsigned short pkh[16 * 1024];   // hi 16 bits of code22, 32 KiB
    __shared__ unsigned char  pkl[16 * 1024];   // lo 6 bits of code22, 16 KiB
    const int t = threadIdx.x, l = t & 63, w = t >> 6;   // w in [0,8)
    const int b = blockIdx.y, row0 = blockIdx.x * 16;
    const int m = l & 15, q4 = l >> 4;

    // A fragments: 16 q rows (hi/lo, two K-halves). A[m][k]: m=lane&15, k=(lane>>4)*8+j
    size_t abase = ((size_t)b * NN + row0 + m) * NDG + q4 * 8;
    s8v ah0 = *(const s8v*)&qh[abase];
    s8v ah1 = *(const s8v*)&qh[abase + 32];
    s8v al0 = *(const s8v*)&ql[abase];
    s8v al1 = *(const s8v*)&ql[abase + 32];

    const int colbase = w * 128;
    #pragma unroll
    for (int tt = 0; tt < 8; ++tt) {
        int col = colbase + tt * 16 + m;
        size_t bbase = ((size_t)b * NN + col) * NDG + q4 * 8;
        s8v bh0 = *(const s8v*)&kh[bbase];
        s8v bh1 = *(const s8v*)&kh[bbase + 32];
        s8v bl0 = *(const s8v*)&kl[bbase];
        s8v bl1 = *(const s8v*)&kl[bbase + 32];
        f4v acc = {0.f, 0.f, 0.f, 0.f};
        acc = __builtin_amdgcn_mfma_f32_16x16x32_bf16(al0, bl0, acc, 0, 0, 0);
        acc = __builtin_amdgcn_mfma_f32_16x16x32_bf16(al1, bl1, acc, 0, 0, 0);
        acc = __builtin_amdgcn_mfma_f32_16x16x32_bf16(ah0, bl0, acc, 0, 0, 0);
        acc = __builtin_amdgcn_mfma_f32_16x16x32_bf16(ah1, bl1, acc, 0, 0, 0);
        acc = __builtin_amdgcn_mfma_f32_16x16x32_bf16(al0, bh0, acc, 0, 0, 0);
        acc = __builtin_amdgcn_mfma_f32_16x16x32_bf16(al1, bh1, acc, 0, 0, 0);
        acc = __builtin_amdgcn_mfma_f32_16x16x32_bf16(ah0, bh0, acc, 0, 0, 0);
        acc = __builtin_amdgcn_mfma_f32_16x16x32_bf16(ah1, bh1, acc, 0, 0, 0);
        // C/D: col=lane&15, row=(lane>>4)*4+reg. Write XOR-swizzled (q4<<4) = ((row>>2)<<4).
        #pragma unroll
        for (int r = 0; r < 4; ++r) {
            int row  = q4 * 4 + r;           // local 0..15
            int grow = row0 + row;
            float s = acc[r] * 0.125f;
            unsigned c22 = (col == grow) ? 0u : pack22(s);
            int pos = row * 1024 + (col ^ (q4 << 4));
            pkh[pos] = (unsigned short)(c22 >> 6);
            pkl[pos] = (unsigned char)(c22 & 63u);
        }
    }
    __syncthreads();

    // wave w selects rows 2w, 2w+1 via butterfly merge-tree; all lanes end with global top-16
    for (int rr = 0; rr < 2; ++rr) {
        const int row = 2 * w + rr, grow = row0 + row;
        const int swz = (row >> 2) << 4;
        unsigned v[16];
        #pragma unroll
        for (int j = 0; j < 16; ++j) {
            int idx = row * 1024 + ((l + 64 * j) ^ swz);   // this index holds col = l+64j
            unsigned c22 = ((unsigned)pkh[idx] << 6) | (unsigned)pkl[idx];
            v[j] = (c22 << 10) | (unsigned)(1023 - (l + 64 * j));
        }
        sort16(v);
        #pragma unroll
        for (int off = 1; off < 64; off <<= 1) {
            unsigned pv[16];
            #pragma unroll
            for (int i = 0; i < 16; ++i) pv[i] = (unsigned)__shfl_xor((int)v[i], off, 64);
            #pragma unroll
            for (int i = 0; i < 8; ++i) {   // c[i]=max(v[i],pv[15-i]) in place (i and 15-i swap-safe)
                unsigned a0 = v[i], b0 = pv[15 - i];
                unsigned a1 = v[15 - i], b1 = pv[i];
                v[i]      = a0 > b0 ? a0 : b0;
                v[15 - i] = a1 > b1 ? a1 : b1;
            }
            clean16(v);
        }
        // v[0..14] = top-15 desc; v[14]=15th, v[15]=16th
        float s15 = dec22(v[14] >> 10), s16 = dec22(v[15] >> 10);
        unsigned e15 = (__float_as_uint(fabsf(s15)) >> 23) & 255u;
        unsigned e16 = (__float_as_uint(fabsf(s16)) >> 23) & 255u;
        unsigned e = e15 > e16 ? e15 : e16;
        float qq = __uint_as_float((e - 17) << 23);    // 22-bit code quantum at this magnitude
        bool flagged = (s15 - s16) < (4.f * qq + 1e-4f);
        if (l < 15) {
            int col = 1023 - (int)(v[l] & 1023u);
            atomicAdd(&deg[b * NN + col], 1);
            atomicOr(&bmp[((size_t)b * NN + col) * 32 + (grow >> 5)], 1u << (grow & 31));
            if (flagged) topk[(b * NN + grow) * 16 + l] = col;
        }
        if (l == 0 && flagged) {
            int idx = atomicAdd(wl_cnt, 1);
            if (idx < 32767) wl[idx] = b * NN + grow;
        }
    }
}

// exact f64 re-selection for worklist rows; patches deg/bitmap by set-diff.
// grid 1024, block 64: ~one block per flagged row, fully concurrent; d-loop double-buffered.
__global__ __launch_bounds__(64) void k_repair(
    const double* __restrict__ qT64, const double* __restrict__ kT64,
    const int* __restrict__ topk, const int* __restrict__ wl_cnt, const int* __restrict__ wl,
    int* __restrict__ deg, unsigned int* __restrict__ bmp)
{
    const int l = threadIdx.x;
    __shared__ double qld[64];
    __shared__ int oldset[15], newset[15];
    const double NEGINF = -__builtin_inf();
    int n = wl_cnt[0]; if (n > 32767) n = 32767;

    for (int i = blockIdx.x; i < n; i += 1024) {
        int rg = wl[i];
        int b = rg >> 10, row = rg & 1023;

        __syncthreads();
        qld[l] = qT64[((size_t)b * NDG + l) * NN + row];
        if (l < 15) oldset[l] = topk[(b * NN + row) * 16 + l];
        __syncthreads();

        double sc[16];
        #pragma unroll
        for (int tt = 0; tt < 16; ++tt) sc[tt] = 0.0;
        const double* kb = &kT64[(size_t)b * NDG * NN];
        double buf[16];
        #pragma unroll
        for (int tt = 0; tt < 16; ++tt) buf[tt] = kb[l + 64 * tt];
        for (int d = 0; d < 64; ++d) {
            double nb[16];
            if (d < 63) {
                const double* kr = kb + (size_t)(d + 1) * NN;
                #pragma unroll
                for (int tt = 0; tt < 16; ++tt) nb[tt] = kr[l + 64 * tt];
            }
            double qd = qld[d];
            #pragma unroll
            for (int tt = 0; tt < 16; ++tt) sc[tt] += qd * buf[tt];
            if (d < 63) {
                #pragma unroll
                for (int tt = 0; tt < 16; ++tt) buf[tt] = nb[tt];
            }
        }
        #pragma unroll
        for (int tt = 0; tt < 16; ++tt) if (l + 64 * tt == row) sc[tt] = NEGINF;

        for (int it = 0; it < 15; ++it) {
            double lv = NEGINF; int lc = 0x7fffffff;
            #pragma unroll
            for (int tt = 0; tt < 16; ++tt)
                if (sc[tt] > lv) { lv = sc[tt]; lc = l + 64 * tt; }
            #pragma unroll
            for (int off = 1; off < 64; off <<= 1) {
                double ov = __shfl_xor(lv, off, 64);
                int    oc = __shfl_xor(lc, off, 64);
                if (ov > lv || (ov == lv && oc < lc)) { lv = ov; lc = oc; }
            }
            #pragma unroll
            for (int tt = 0; tt < 16; ++tt) if (l + 64 * tt == lc) sc[tt] = NEGINF;
            if (l == 0) newset[it] = lc;
        }
        __syncthreads();
        if (l < 15) {
            int cn = newset[l];
            bool found = false;
            #pragma unroll
            for (int j = 0; j < 15; ++j) found = found || (oldset[j] == cn);
            if (!found) {
                atomicAdd(&deg[b * NN + cn], 1);
                atomicOr(&bmp[((size_t)b * NN + cn) * 32 + (row >> 5)], 1u << (row & 31));
            }
            int co = oldset[l];
            found = false;
            #pragma unroll
            for (int j = 0; j < 15; ++j) found = found || (newset[j] == co);
            if (!found) {
                atomicSub(&deg[b * NN + co], 1);
                atomicAnd(&bmp[((size_t)b * NN + co) * 32 + (row >> 5)], ~(1u << (row & 31)));
            }
        }
    }
}

// gather per target via compacted LDS edge list + LDS norm table (dinv folded here).
// grid (1024,32), block 128 (f = thread).
__global__ __launch_bounds__(128) void k_gather(
    const float* __restrict__ h, const float* __restrict__ bg,
    const int* __restrict__ deg, const unsigned int* __restrict__ bmp,
    float* __restrict__ tmp)
{
    __shared__ int list[1024];
    __shared__ float nrm[1024];
    __shared__ int scnt;
    const int tgt = blockIdx.x, b = blockIdx.y, t = threadIdx.x;
    if (t < 32) {
        unsigned word = bmp[((size_t)b * NN + tgt) * 32 + t];
        int pc = __popc(word);
        int pre = pc;
        #pragma unroll
        for (int d = 1; d < 32; d <<= 1) {
            int o = __shfl_up(pre, d, 32);
            if (t >= d) pre += o;
        }
        if (t == 31) scnt = pre;
        int idx = pre - pc;
        while (word) {
            int s = __ffs(word) - 1;
            word &= word - 1;
            list[idx++] = t * 32 + s;
        }
    }
    __syncthreads();
    const int cnt = scnt;
    for (int e = t; e < cnt; e += 128)
        nrm[e] = rsqrtf((float)(deg[b * NN + list[e]] + 2));
    __syncthreads();
    const int f = t;
    float dt = rsqrtf((float)(deg[b * NN + tgt] + 2));
    float acc = 2.0f * dt * h[((size_t)b * NN + tgt) * NF + f];
    for (int e = 0; e < cnt; ++e) {
        int src = list[e];
        acc += h[((size_t)b * NN + src) * NF + f] * nrm[e];
    }
    tmp[((size_t)b * NN + tgt) * NF + f] = bg[f] + dt * acc;
}

// [b][n][f] -> [b][f][n]. grid (32, 4, 32), block 256.
__global__ __launch_bounds__(256) void k_transpose(const float* __restrict__ tmp,
                                                   float* __restrict__ out)
{
    __shared__ float tile[32][33];
    const int t = threadIdx.x;
    const int n0 = blockIdx.x * 32, f0 = blockIdx.y * 32, b = blockIdx.z;
    const int c = t & 31, rb = t >> 5;
    #pragma unroll
    for (int i = 0; i < 4; ++i) {
        int r = rb + i * 8;
        tile[r][c] = tmp[((size_t)b * NN + n0 + r) * NF + f0 + c];
    }
    __syncthreads();
    #pragma unroll
    for (int i = 0; i < 4; ++i) {
        int r = rb + i * 8;
        out[((size_t)b * NF + f0 + r) * NN + n0 + c] = tile[c][r];
    }
}

extern "C" void kernel_launch(void* const* d_in, const int* in_sizes, int n_in,
                              void* d_out, int out_size, void* d_ws, size_t ws_size,
                              hipStream_t stream)
{
    const float* x  = (const float*)d_in[0];
    const float* Wq = (const float*)d_in[1];
    const float* bq = (const float*)d_in[2];
    const float* Wk = (const float*)d_in[3];
    const float* bk = (const float*)d_in[4];
    const float* Wg = (const float*)d_in[5];
    const float* bg = (const float*)d_in[6];
    float* out = (float*)d_out;
    char* ws = (char*)d_ws;

    unsigned short* qh = (unsigned short*)(ws + OFF_QH);
    unsigned short* ql = (unsigned short*)(ws + OFF_QL);
    unsigned short* kh = (unsigned short*)(ws + OFF_KH);
    unsigned short* kl = (unsigned short*)(ws + OFF_KL);
    float*          h   = (float*)(ws + OFF_H);
    int*            deg = (int*)(ws + OFF_DEG);
    unsigned int*   bmp = (unsigned int*)(ws + OFF_BMP);
    int*            wlc = (int*)(ws + OFF_WL);
    int*            wl  = wlc + 1;
    int*            tpk = (int*)(ws + OFF_TOPK);
    double*         Wq64 = (double*)(ws + OFF_W64);
    double*         Wk64 = Wq64 + 8192;
    double*         qT64 = (double*)(ws + OFF_QT64);
    double*         kT64 = (double*)(ws + OFF_KT64);
    float*          tmp  = (float*)(ws + OFF_TMP);

    k_upcast<<<32, 256, 0, stream>>>(Wq, Wk, Wq64, Wk64);
    // zero range: deg + bmp + wl_cnt = 4,325,392 B = 270337 uint4 (done inside k_prep)
    k_prep<<<dim3(16, 2, 32), 256, 0, stream>>>(x, bq, bk, Wq64, Wk64, Wg,
                                                qh, ql, kh, kl, qT64, kT64, h,
                                                (uint4*)(ws + OFF_DEG), 270337);
    k_score<<<dim3(64, 32), 512, 0, stream>>>(qh, ql, kh, kl, deg, bmp, tpk, wlc, wl);
    k_repair<<<1024, 64, 0, stream>>>(qT64, kT64, tpk, wlc, wl, deg, bmp);
    k_gather<<<dim3(1024, 32), 128, 0, stream>>>(h, bg, deg, bmp, tmp);
    k_transpose<<<dim3(32, 4, 32), 256, 0, stream>>>(tmp, out);
}